// Round 9
// baseline (108.702 us; speedup 1.0000x reference)
//
#include <hip/hip_runtime.h>

#define T_LEN 256
#define NG 26              // 26 groups x 16 steps = 416 steps (max s needed = 414)

__device__ __forceinline__ float ex2(float x) { return __builtin_amdgcn_exp2f(x); }
__device__ __forceinline__ float rcp1p(float e) { return __builtin_amdgcn_rcpf(1.0f + e); }
__device__ __forceinline__ float rcpf_(float x) { return __builtin_amdgcn_rcpf(x); }

// Eigen/XLA rational tanh: tanh(x) ~= x*P(x^2) / Q(x^2), |x| <= ~7.9, err <1e-4.
// Denominator rcp overlaps numerator Horner chain -> latency ~ 24 + T_rcp.
__device__ __forceinline__ float tanh_rat(float x) {
    const float a1 = 4.89352455891786e-03f, a3 = 6.37261928875436e-04f,
                a5 = 1.48572235717979e-05f, a7 = 5.12229709037114e-08f,
                a9 = -8.60467152213735e-11f, a11 = 2.00018790482477e-13f,
                a13 = -2.76076847742355e-16f;
    const float b0 = 4.89352518554385e-03f, b2 = 2.26843463243900e-03f,
                b4 = 1.18534705686654e-04f, b6 = 1.19825839466702e-06f;
    float y = x * x;
    float q = fmaf(y, fmaf(y, fmaf(y, b6, b4), b2), b0);        // ready early
    float rq = rcpf_(q);                                        // overlaps p below
    float p = fmaf(y, fmaf(y, fmaf(y, fmaf(y, fmaf(y, fmaf(y, a13, a11), a9), a7), a5), a3), a1);
    return (x * p) * rq;
}

// wave_shr:1 (0x138): lane i <- lane i-1 (lane 0 keeps own). VALU pipe.
__device__ __forceinline__ float dpp_wave_shr1(float v) {
    int i = __float_as_int(v);
    return __int_as_float(__builtin_amdgcn_update_dpp(i, i, 0x138, 0xF, 0xF, false));
}
// wave_rol:1 (0x134): lane i <- lane (i+1)%64.
__device__ __forceinline__ float dpp_wave_rol1(float v) {
    int i = __float_as_int(v);
    return __int_as_float(__builtin_amdgcn_update_dpp(i, i, 0x134, 0xF, 0xF, false));
}

// R7 structure (proven): TWO waves, 1 layer/lane, cell (l,t) at step
// s = t + l + 32*(l>=64); ring + group-prefetch seam; conveyors for x and out.
// R9 change: r and n activations via rational tanh (chain ~24+T each instead of
// 8+2T), h-update h' = fma(n, 1-z, z*h) with both coefficients off-chain.
//  - r = 0.5 + 0.5*tanh(u_r/2): half-scale folded into wi_r2/c_r2; the 0.5
//    offset folded into un: un = fma(t_r, g_nh, base), base = fma(wi_n,in,bplus),
//    bplus = bi_n + g_nh, g_nh = 0.5*(wh_n*h + bh_n)  (all off-chain).
//  - n = tanh_rat(clamp(un, ±7.9)) directly (|un| <= ~7.5 analytically).
//  - z stays hardware exp2 (off the critical chain; ready before h-update).
//  - validity freeze: z := 1 when t invalid -> h' = n*0 + 1*h == h exactly
//    (n always finite: ring zero-inited, no NaN sources).
__global__ __launch_bounds__(128, 1) void gru_stack_wavefront(
    const float* __restrict__ x,
    const float* __restrict__ w_ih,
    const float* __restrict__ w_hh,
    const float* __restrict__ b_ih,
    const float* __restrict__ b_hh,
    float* __restrict__ out)
{
    __shared__ float ring[2 * 64 * 64];   // [wid][slot][lane], 32 KiB
    const int tid  = threadIdx.x;         // 0..127 == layer index
    const int lane = tid & 63;
    const int wid  = tid >> 6;

    #pragma unroll 4
    for (int m = tid; m < 2 * 64 * 64; m += 128) ring[m] = 0.0f;

    const float L1 = -1.4426950408889634f;   // -log2(e) (z-gate exp2 scale)

    // r-gate (tanh-half form, UNSCALED weights * 0.5)
    const float wi_r2 = 0.5f * w_ih[3 * tid + 0], wh_r2 = 0.5f * w_hh[3 * tid + 0];
    const float b_r2  = 0.5f * (b_ih[3 * tid + 0] + b_hh[3 * tid + 0]);
    // z-gate (hardware sigmoid, exp2-scaled)
    const float wi_zs = L1 * w_ih[3 * tid + 1], wh_zs = L1 * w_hh[3 * tid + 1];
    const float b_zs  = L1 * (b_ih[3 * tid + 1] + b_hh[3 * tid + 1]);
    // n-path (UNSCALED; tanh direct). g_nh = 0.5*(wh_n*h + bh_n)
    const float wi_n  = w_ih[3 * tid + 2], bi_n = b_ih[3 * tid + 2];
    const float wh_n2 = 0.5f * w_hh[3 * tid + 2], bh_n2 = 0.5f * b_hh[3 * tid + 2];

    float xc0 = x[lane];
    float xc1 = x[lane + 64];
    float xc2 = x[lane + 128];
    float xc3 = x[lane + 192];

    float h = 0.0f;
    // h-dependent precomputes (h = 0 now)
    float c_r2  = b_r2;               // 0.5*(wh_r*h) + b_r2
    float c_zs  = b_zs;               // L1*(wh_z*h) + b_zs
    float g_nh  = bh_n2;              // 0.5*(wh_n*h + bh_n)
    float bplus = bi_n + g_nh;

    float pcur[16], pnext[16];
    #pragma unroll
    for (int k = 0; k < 16; ++k) { pcur[k] = 0.0f; pnext[k] = 0.0f; }

    float ov = 0.0f;                  // output conveyor (wave1)
    float xq = xc0;                   // x conveyor (wave0)
    int t = -lane - 96 * wid - 1;     // ++ at step top -> t = s - lane - 96*wid

    const bool is_l0 = (lane == 0);
    const bool is_w1 = (wid == 1);
    float* ringw = &ring[wid * 4096];

    __syncthreads();                  // ring init visible

    for (int g = 0; g < NG; ++g) {
        if      (g == 4)  xq = xc1;   // chunk switch at s = 64,128,192
        else if (g == 8)  xq = xc2;
        else if (g == 12) xq = xc3;

        if (is_w1) {                  // prefetch NEXT group's boundary vals
            const int base = 16 * g - 17;
            #pragma unroll
            for (int k = 0; k < 16; ++k)
                pnext[k] = ring[((base + k) & 63) * 64 + 63];   // plane 0, broadcast
        }

        const int sb = (16 * g) & 63;

        #pragma unroll
        for (int k = 0; k < 16; ++k) {
            ++t;
            const bool valid = (unsigned)t < (unsigned)T_LEN;

            float alt = is_w1 ? pcur[k] : xq;        // ready since last group
            float shifted = dpp_wave_shr1(h);        // chain start
            float in = is_l0 ? alt : shifted;

            // --- r gate: rational tanh-half ---
            float u_r = fmaf(wi_r2, in, c_r2);       // = u_r_full / 2, |.| <= ~3.3
            float t_r = tanh_rat(u_r);               // r = 0.5 + 0.5*t_r (folded below)

            // --- z gate: hardware sigmoid (off-chain) ---
            float z = rcp1p(ex2(fmaf(wi_zs, in, c_zs)));
            z = valid ? z : 1.0f;                    // freeze when t invalid
            float omz = 1.0f - z;                    // off-chain
            float zh  = z * h;                       // off-chain

            // --- n: un = base + t_r*g_nh; tanh direct ---
            float base_n = fmaf(wi_n, in, bplus);    // parallel with r-chain
            float un = fmaf(t_r, g_nh, base_n);
            un = __builtin_amdgcn_fmed3f(un, -7.9f, 7.9f);   // safety clamp
            float n = tanh_rat(un);

            h = fmaf(n, omz, zh);                    // (1-z)*n + z*h

            // precomputes for next step (off the input-critical chain)
            c_r2  = fmaf(wh_r2, h, b_r2);
            c_zs  = fmaf(wh_zs, h, b_zs);
            g_nh  = fmaf(wh_n2, h, bh_n2);
            bplus = bi_n + g_nh;

            ringw[((sb + k) & 63) * 64 + lane] = h;  // publish (fire-and-forget)

            // output conveyor: rotate, inject layer-127 h at lane 63
            float rot = dpp_wave_rol1(ov);
            ov = (lane == 63) ? h : rot;
            xq = dpp_wave_rol1(xq);                  // x conveyor advance

            if (k == 14) {                           // stores at s=222,286,350,414
                if (is_w1 && (g & 3) == 1 && g >= 13)
                    out[16 * g - 208 + lane] = ov;   // coalesced 64-lane store
            }
        }

        if (is_w1) {
            #pragma unroll
            for (int k = 0; k < 16; ++k) pcur[k] = pnext[k];
        }
        __syncthreads();                             // bounds wave drift (<16 steps)
    }
}

extern "C" void kernel_launch(void* const* d_in, const int* in_sizes, int n_in,
                              void* d_out, int out_size, void* d_ws, size_t ws_size,
                              hipStream_t stream) {
    const float* x    = (const float*)d_in[0];  // [1,256]
    const float* w_ih = (const float*)d_in[1];  // [128,3,1]
    const float* w_hh = (const float*)d_in[2];  // [128,3,1]
    const float* b_ih = (const float*)d_in[3];  // [128,3]
    const float* b_hh = (const float*)d_in[4];  // [128,3]
    float* out = (float*)d_out;                 // [1,256]

    gru_stack_wavefront<<<1, 128, 0, stream>>>(x, w_ih, w_hh, b_ih, b_hh, out);
}

// Round 10
// 97.658 us; speedup vs baseline: 1.1131x; 1.1131x over previous
//
#include <hip/hip_runtime.h>

#define T_LEN 256
#define NG 26              // 26 groups x 16 steps = 416 steps (max s needed = 414)

__device__ __forceinline__ float ex2(float x) { return __builtin_amdgcn_exp2f(x); }
__device__ __forceinline__ float rcpf_(float x) { return __builtin_amdgcn_rcpf(x); }

// wave_shr:1 (0x138): lane i <- lane i-1 (lane 0 keeps own). VALU pipe.
__device__ __forceinline__ float dpp_wave_shr1(float v) {
    int i = __float_as_int(v);
    return __int_as_float(__builtin_amdgcn_update_dpp(i, i, 0x138, 0xF, 0xF, false));
}

// TWO waves, 1 layer/lane, cell (l,t) at step s = t + lane + 96*wid.
// R10 trims on the R7 skeleton (empirical law: per-step = issue + chain):
//  - `in` for step s+1 computed at TAIL of step s (dpp + seam select off-chain);
//    chain is now fma->ex2->add->rcp->fma->ex2->add->rcp->fma only.
//  - h-update single fma: n = 2*s_n-1 folded: h' = s_n*(2-2z) + (z*h + z-1),
//    both coefficients computed off-chain from z (ready mid-step).
//  - no conveyors: BOTH waves take their seam feed from group-top broadcast
//    prefetch (wave0 <- sx[s+1], wave1 <- ring slot (s+1)-33); pk[k] = feed
//    for the tail of step 16g+k. All slots written before this group's barrier.
//  - ring written by wave0 only (only plane0 col 63 is ever read).
//  - validity: z := 1 when t invalid => two_omz=0, zh_m=h => h'==h exactly.
__global__ __launch_bounds__(128, 1) void gru_stack_wavefront(
    const float* __restrict__ x,
    const float* __restrict__ w_ih,
    const float* __restrict__ w_hh,
    const float* __restrict__ b_ih,
    const float* __restrict__ b_hh,
    float* __restrict__ out)
{
    __shared__ float plane0[64 * 64];     // wave0's h history [slot][lane], 16 KiB
    __shared__ float sx[T_LEN];
    const int tid  = threadIdx.x;         // 0..127 == layer index
    const int lane = tid & 63;
    const int wid  = tid >> 6;

    sx[tid] = x[tid];                     // tid<128
    sx[tid + 128] = x[tid + 128];
    #pragma unroll
    for (int m = tid; m < 64 * 64; m += 128) plane0[m] = 0.0f;

    const float L1 = -1.4426950408889634f;   // -log2(e)   (sigmoid scale)
    const float L2 = -2.8853900817779268f;   // -2*log2(e) (tanh-as-sigmoid scale)

    const float wi_r = L1 * w_ih[3 * tid + 0], wh_r = L1 * w_hh[3 * tid + 0];
    const float b_r  = L1 * (b_ih[3 * tid + 0] + b_hh[3 * tid + 0]);
    const float wi_z = L1 * w_ih[3 * tid + 1], wh_z = L1 * w_hh[3 * tid + 1];
    const float b_z  = L1 * (b_ih[3 * tid + 1] + b_hh[3 * tid + 1]);
    const float wi_n = L2 * w_ih[3 * tid + 2], bi_n = L2 * b_ih[3 * tid + 2];
    const float wh_n = L2 * w_hh[3 * tid + 2], bh_n = L2 * b_hh[3 * tid + 2];

    const float x0 = x[0];

    float h = 0.0f;
    float c_r = b_r, c_z = b_z, g_n = bh_n;   // h-dependent precomputes (h=0)

    const bool is_l0 = (lane == 0);
    const bool is_w0 = (wid == 0);

    // first input (step 0 head): wave0 lane0 <- x[0]; everyone else 0 (h==0)
    float in = (is_l0 && is_w0) ? x0 : 0.0f;

    float pk[16];
    int t = -lane - 96 * wid - 1;             // ++ at head -> t = s - lane - 96*wid

    __syncthreads();                          // sx + plane0 init visible

    for (int g = 0; g < NG; ++g) {
        // group-top prefetch: pk[k] = seam feed consumed at TAIL of step 16g+k
        // (i.e. the input for step 16g+k+1). Broadcast reads, off-chain.
        if (is_w0) {
            #pragma unroll
            for (int k = 0; k < 16; ++k)
                pk[k] = sx[(16 * g + k + 1) & (T_LEN - 1)];       // x[s+1]
        } else {
            #pragma unroll
            for (int k = 0; k < 16; ++k)
                pk[k] = plane0[((16 * g + k - 32) & 63) * 64 + 63]; // h(63, (s+1)-33)
        }

        #pragma unroll
        for (int k = 0; k < 16; ++k) {
            ++t;
            const bool valid = (unsigned)t < (unsigned)T_LEN;

            // ---- chain: fma -> ex2 -> add -> rcp -> fma -> ex2 -> add -> rcp -> fma
            float u_r = fmaf(wi_r, in, c_r);
            float u_z = fmaf(wi_z, in, c_z);          // z path (off-chain)
            float bse = fmaf(wi_n, in, bi_n);         // parallel with r path
            float r = rcpf_(1.0f + ex2(u_r));
            float z = rcpf_(1.0f + ex2(u_z));
            z = valid ? z : 1.0f;                     // freeze when t invalid
            float two_omz = fmaf(-2.0f, z, 2.0f);     // 2*(1-z), off-chain
            float zh_m = fmaf(z, h, z - 1.0f);        // z*h - (1-z), off-chain
            float un = fmaf(r, g_n, bse);
            float s_n = rcpf_(1.0f + ex2(un));        // n = 2*s_n - 1 (folded)
            h = fmaf(s_n, two_omz, zh_m);             // (1-z)*n + z*h

            // ---- tail (off the next step's chain head) ----
            c_r = fmaf(wh_r, h, b_r);
            c_z = fmaf(wh_z, h, b_z);
            g_n = fmaf(wh_n, h, bh_n);

            if (is_w0) plane0[((16 * g + k) & 63) * 64 + lane] = h;  // wave-uniform
            if (tid == 127 && valid) out[t] = h;                     // layer 127

            // input for step s+1, computed off-chain at tail
            float sh = dpp_wave_shr1(h);
            in = is_l0 ? pk[k] : sh;
        }
        __syncthreads();    // bounds wave drift (<16 steps); orders ring writes
    }
}

extern "C" void kernel_launch(void* const* d_in, const int* in_sizes, int n_in,
                              void* d_out, int out_size, void* d_ws, size_t ws_size,
                              hipStream_t stream) {
    const float* x    = (const float*)d_in[0];  // [1,256]
    const float* w_ih = (const float*)d_in[1];  // [128,3,1]
    const float* w_hh = (const float*)d_in[2];  // [128,3,1]
    const float* b_ih = (const float*)d_in[3];  // [128,3]
    const float* b_hh = (const float*)d_in[4];  // [128,3]
    float* out = (float*)d_out;                 // [1,256]

    gru_stack_wavefront<<<1, 128, 0, stream>>>(x, w_ih, w_hh, b_ih, b_hh, out);
}